// Round 1
// 463.982 us; speedup vs baseline: 1.0425x; 1.0425x over previous
//
#include <hip/hip_runtime.h>
#include <hip/hip_bf16.h>

// GroupedMLP: E=8, H=1024, I=2816, T=8192. fp32 in HBM, bf16 MFMA compute.
//   0) convx:   X fp32 -> xb bf16 (staged inside d_out; gemm3 overwrites later)
//   1) tconvGU: gate+up fp32 [E,H,I] -> gateT/upT bf16 [E,I,H]
//               NEW: float4-coalesced loads -> XOR-swizzled LDS transpose -> u16x8 stores
//   2) gemm12:  inter = silu(xb@gate)*(xb@up)  [BK=64, chunk-swizzled; 854 TF anchor]
//   3) tconvD:  down fp32 [E,I,H] -> downT bf16 [E,H,I] (same new tconv)
//   4) gemm3:   out = inter @ down, NEW: BM=128 BN=128 BK=64 (anchor-density shape,
//               32 MFMA + 8 staging loads per K-step; grid 8x64 = 512 blocks = 2/CU)
// Chunk swizzle (GEMMs): LDS 16B-chunk for (row m, k-chunk j) lives at m*8 + (j ^ (m&7)).
// tconv LDS swizzle: element (c,r) at u16 index c*64 + ((r>>3)^(c>>3))*8 + (r&7).
// ws: 3 x 46,137,344 B (gateT/downT, upT, inter).

#define E_ 8
#define H_ 1024
#define I_ 2816
#define T_ 8192

typedef unsigned short u16;
typedef __attribute__((ext_vector_type(8))) short s16x8;
typedef __attribute__((ext_vector_type(8))) unsigned short u16x8;
typedef __attribute__((ext_vector_type(4))) float f32x4;

__device__ __forceinline__ void async16(const u16* g, u16* l) {
  __builtin_amdgcn_global_load_lds((__attribute__((address_space(1))) void*)g,
                                   (__attribute__((address_space(3))) void*)l, 16, 0, 0);
}

__device__ __forceinline__ u16 f2b(float f) {
  union { __hip_bfloat16 h; u16 u; } c;
  c.h = __float2bfloat16(f);
  return c.u;
}

// ---------------- convert X fp32 -> bf16 ----------------
__global__ __launch_bounds__(256) void convx_k(const float* __restrict__ x,
                                               u16* __restrict__ xb) {
  size_t i = ((size_t)blockIdx.x * 256 + threadIdx.x) * 8;
  float4 v0 = *(const float4*)(x + i);
  float4 v1 = *(const float4*)(x + i + 4);
  u16x8 b;
  b[0] = f2b(v0.x); b[1] = f2b(v0.y); b[2] = f2b(v0.z); b[3] = f2b(v0.w);
  b[4] = f2b(v1.x); b[5] = f2b(v1.y); b[6] = f2b(v1.z); b[7] = f2b(v1.w);
  *(u16x8*)(xb + i) = b;
}

// ---- transpose+convert via swizzled LDS: out[c][r] bf16 = in[r][c] fp32, 64x64 tile ----
// Phase 1: thread t loads rows rl=(t>>3)*2, rl+1, cols cl=(t&7)*8..+7 as 4x float4
//          (16 consecutive lanes cover 2 full 256B row segments -> coalesced 16B/lane).
//          Packs (r,r+1) bf16 pairs, writes 8x b32 into swizzled LDS:
//          lt[(cl+j)*64 + (((rl>>3)^(cl>>3))<<3) + (rl&7)]  -> banks spread, 2-way max (free).
// Phase 2: thread t owns out-row c=t>>2, r-segment rs=(t&3)*16: two swizzled b128 reads
//          (8 lanes per 16B slot = exactly minimum -> conflict-free), two 16B global stores
//          (4 lanes cover 128B contiguous per out row).
template <int R, int C>
__device__ __forceinline__ void tconv_tile(const float* __restrict__ in,
                                           u16* __restrict__ out,
                                           int bx, int by, int t) {
  __shared__ u16 lt[64 * 64];
  const int c0 = bx * 64, r0 = by * 64;

  const int rl = (t >> 3) * 2;
  const int cl = (t & 7) * 8;
  const float* p = in + (size_t)(r0 + rl) * C + (c0 + cl);
  float4 v0 = *(const float4*)(p);
  float4 v1 = *(const float4*)(p + 4);
  float4 v2 = *(const float4*)(p + C);
  float4 v3 = *(const float4*)(p + C + 4);

  float lo[8] = {v0.x, v0.y, v0.z, v0.w, v1.x, v1.y, v1.z, v1.w};
  float hi[8] = {v2.x, v2.y, v2.z, v2.w, v3.x, v3.y, v3.z, v3.w};
  const int chunk = ((rl >> 3) ^ (cl >> 3)) << 3;  // constant per thread (j<8 keeps c>>3 fixed)
  u16* wp = lt + cl * 64 + chunk + (rl & 7);
#pragma unroll
  for (int j = 0; j < 8; ++j) {
    unsigned pk = (unsigned)f2b(lo[j]) | ((unsigned)f2b(hi[j]) << 16);
    *(unsigned*)(wp + j * 64) = pk;
  }
  __syncthreads();

  const int c = t >> 2;
  const int rs = (t & 3) * 16;
  const int rc = rs >> 3;
  u16x8 o0 = *(const u16x8*)(lt + c * 64 + ((rc ^ (c >> 3)) << 3));
  u16x8 o1 = *(const u16x8*)(lt + c * 64 + (((rc + 1) ^ (c >> 3)) << 3));
  u16* op = out + (size_t)(c0 + c) * R + (r0 + rs);
  *(u16x8*)(op) = o0;
  *(u16x8*)(op + 8) = o1;
}

__global__ __launch_bounds__(256) void tconvGU_k(const float* __restrict__ G,
                                                 const float* __restrict__ U,
                                                 u16* __restrict__ GT,
                                                 u16* __restrict__ UT) {
  const int z = blockIdx.z;
  const size_t eoff = (size_t)(z >> 1) * (size_t)H_ * I_;
  const float* in = ((z & 1) ? U : G) + eoff;
  u16* out = ((z & 1) ? UT : GT) + eoff;
  tconv_tile<H_, I_>(in, out, blockIdx.x, blockIdx.y, threadIdx.x);
}

__global__ __launch_bounds__(256) void tconvD_k(const float* __restrict__ D,
                                                u16* __restrict__ DT) {
  const size_t eoff = (size_t)blockIdx.z * (size_t)H_ * I_;
  tconv_tile<I_, H_>(D + eoff, DT + eoff, blockIdx.x, blockIdx.y, threadIdx.x);
}

// ---------------- fused gate/up GEMM + SwiGLU, BK=64, chunk-swizzled (ANCHOR) ----------------
__global__ __launch_bounds__(256, 2) void gemm12_k(
    const u16* __restrict__ X, const u16* __restrict__ GT,
    const u16* __restrict__ UT, const int* __restrict__ tpe,
    u16* __restrict__ inter) {
  __shared__ u16 sA[128 * 64];
  __shared__ u16 sG[64 * 64];
  __shared__ u16 sU[64 * 64];
  const int t = threadIdx.x;
  const int m0 = blockIdx.y * 128;
  const int n0 = blockIdx.x * 64;

  int e = 0, seg_end = T_;
  {
    int s = 0;
    for (int i = 0; i < E_; ++i) {
      int c = tpe[i];
      if (m0 < s + c) { e = i; seg_end = s + c; break; }
      s += c;
    }
  }
  const u16* GTe = GT + (size_t)e * I_ * H_;
  const u16* UTe = UT + (size_t)e * I_ * H_;

  const int sj = ((t & 7) ^ ((t >> 3) & 7)) * 8;
  const u16* gA = X + (size_t)(m0 + (t >> 3)) * H_ + sj;
  const u16* gG = GTe + (size_t)(n0 + (t >> 3)) * H_ + sj;
  const u16* gU = UTe + (size_t)(n0 + (t >> 3)) * H_ + sj;
  u16* lA = sA + t * 8;
  u16* lG = sG + t * 8;
  u16* lU = sU + t * 8;

  const int l = t & 63, w = t >> 6;
  const int wm = (w & 1) * 64, wn = (w >> 1) * 32;
  const int c0 = (((l >> 4) ^ (l & 7))) * 8;
  const u16* fA = sA + (size_t)(wm + (l & 15)) * 64;
  const u16* fG = sG + (size_t)(wn + (l & 15)) * 64;
  const u16* fU = sU + (size_t)(wn + (l & 15)) * 64;

  f32x4 accG[4][2], accU[4][2];
#pragma unroll
  for (int mi = 0; mi < 4; ++mi)
#pragma unroll
    for (int ni = 0; ni < 2; ++ni) {
      accG[mi][ni] = (f32x4){0.f, 0.f, 0.f, 0.f};
      accU[mi][ni] = (f32x4){0.f, 0.f, 0.f, 0.f};
    }

  for (int k0 = 0; k0 < H_; k0 += 64) {
    async16(gA + k0, lA);
    async16(gA + 32 * H_ + k0, lA + 2048);
    async16(gA + 64 * H_ + k0, lA + 4096);
    async16(gA + 96 * H_ + k0, lA + 6144);
    async16(gG + k0, lG);
    async16(gG + 32 * H_ + k0, lG + 2048);
    async16(gU + k0, lU);
    async16(gU + 32 * H_ + k0, lU + 2048);
    __syncthreads();
#pragma unroll
    for (int ks = 0; ks < 2; ++ks) {
      const int co = c0 ^ (ks * 32);
      s16x8 aF[4], gF[2], uF[2];
#pragma unroll
      for (int mi = 0; mi < 4; ++mi) aF[mi] = *(const s16x8*)(fA + mi * 1024 + co);
#pragma unroll
      for (int ni = 0; ni < 2; ++ni) {
        gF[ni] = *(const s16x8*)(fG + ni * 1024 + co);
        uF[ni] = *(const s16x8*)(fU + ni * 1024 + co);
      }
#pragma unroll
      for (int mi = 0; mi < 4; ++mi)
#pragma unroll
        for (int ni = 0; ni < 2; ++ni) {
          accG[mi][ni] = __builtin_amdgcn_mfma_f32_16x16x32_bf16(aF[mi], gF[ni], accG[mi][ni], 0, 0, 0);
          accU[mi][ni] = __builtin_amdgcn_mfma_f32_16x16x32_bf16(aF[mi], uF[ni], accU[mi][ni], 0, 0, 0);
        }
    }
    __syncthreads();
  }

  const int colb = l & 15, rowb = (l >> 4) * 4;
#pragma unroll
  for (int mi = 0; mi < 4; ++mi)
#pragma unroll
    for (int ni = 0; ni < 2; ++ni) {
      const size_t gcol = (size_t)(n0 + wn + ni * 16 + colb);
#pragma unroll
      for (int r = 0; r < 4; ++r) {
        int grow = m0 + wm + mi * 16 + rowb + r;
        if (grow < seg_end) {
          float o1 = accG[mi][ni][r];
          float o2 = accU[mi][ni][r];
          float sv = o1 / (1.f + __expf(-o1));
          inter[(size_t)grow * I_ + gcol] = f2b(sv * o2);
        }
      }
    }
}

// ------- down-proj GEMM: BM=128, BN=128, BK=64 chunk-swizzled (anchor-density shape) -------
// grid 8 x 64 = 512 blocks = 2/CU; per-wave 64x64; 32 MFMA + 8 staging loads per K-step.
__global__ __launch_bounds__(256, 2) void gemm3_k(
    const u16* __restrict__ A, const u16* __restrict__ DT,
    const int* __restrict__ tpe, float* __restrict__ out) {
  __shared__ u16 sA[128 * 64];  // 16 KB
  __shared__ u16 sB[128 * 64];  // 16 KB
  const int t = threadIdx.x;
  const int m0 = blockIdx.y * 128;
  const int n0 = blockIdx.x * 128;

  int e = 0, seg_end = T_;
  {
    int s = 0;
    for (int i = 0; i < E_; ++i) {
      int c = tpe[i];
      if (m0 < s + c) { e = i; seg_end = s + c; break; }
      s += c;
    }
  }
  const u16* DTe = DT + (size_t)e * H_ * I_;

  const int sj = ((t & 7) ^ ((t >> 3) & 7)) * 8;
  const u16* gA = A + (size_t)(m0 + (t >> 3)) * I_ + sj;
  const u16* gB = DTe + (size_t)(n0 + (t >> 3)) * I_ + sj;
  u16* lA = sA + t * 8;
  u16* lB = sB + t * 8;

  const int l = t & 63, w = t >> 6;
  const int wm = (w & 1) * 64, wn = (w >> 1) * 64;
  const int c0 = (((l >> 4) ^ (l & 7))) * 8;
  const u16* fA = sA + (size_t)(wm + (l & 15)) * 64;
  const u16* fB = sB + (size_t)(wn + (l & 15)) * 64;

  f32x4 acc[4][4];
#pragma unroll
  for (int mi = 0; mi < 4; ++mi)
#pragma unroll
    for (int ni = 0; ni < 4; ++ni) acc[mi][ni] = (f32x4){0.f, 0.f, 0.f, 0.f};

  for (int k0 = 0; k0 < I_; k0 += 64) {
    async16(gA + k0, lA);
    async16(gA + 32 * I_ + k0, lA + 2048);
    async16(gA + 64 * I_ + k0, lA + 4096);
    async16(gA + 96 * I_ + k0, lA + 6144);
    async16(gB + k0, lB);
    async16(gB + 32 * I_ + k0, lB + 2048);
    async16(gB + 64 * I_ + k0, lB + 4096);
    async16(gB + 96 * I_ + k0, lB + 6144);
    __syncthreads();
#pragma unroll
    for (int ks = 0; ks < 2; ++ks) {
      const int co = c0 ^ (ks * 32);
      s16x8 aF[4], bF[4];
#pragma unroll
      for (int mi = 0; mi < 4; ++mi) aF[mi] = *(const s16x8*)(fA + mi * 1024 + co);
#pragma unroll
      for (int ni = 0; ni < 4; ++ni) bF[ni] = *(const s16x8*)(fB + ni * 1024 + co);
#pragma unroll
      for (int mi = 0; mi < 4; ++mi)
#pragma unroll
        for (int ni = 0; ni < 4; ++ni)
          acc[mi][ni] = __builtin_amdgcn_mfma_f32_16x16x32_bf16(aF[mi], bF[ni], acc[mi][ni], 0, 0, 0);
    }
    __syncthreads();
  }

  const int colb = l & 15, rowb = (l >> 4) * 4;
#pragma unroll
  for (int mi = 0; mi < 4; ++mi)
#pragma unroll
    for (int ni = 0; ni < 4; ++ni) {
      const size_t gcol = (size_t)(n0 + wn + ni * 16 + colb);
#pragma unroll
      for (int r = 0; r < 4; ++r) {
        int grow = m0 + wm + mi * 16 + rowb + r;
        if (grow < seg_end) out[(size_t)grow * H_ + gcol] = acc[mi][ni][r];
      }
    }
}

extern "C" void kernel_launch(void* const* d_in, const int* in_sizes, int n_in,
                              void* d_out, int out_size, void* d_ws, size_t ws_size,
                              hipStream_t stream) {
  const float* X = (const float*)d_in[0];
  const float* G = (const float*)d_in[1];
  const float* U = (const float*)d_in[2];
  const float* D = (const float*)d_in[3];
  const int* tpe = (const int*)d_in[4];
  float* out = (float*)d_out;

  const size_t W = (size_t)E_ * H_ * I_;
  if (ws_size < 3 * W * sizeof(u16)) return;
  u16* r0 = (u16*)d_ws;   // gateT, later downT
  u16* r1 = r0 + W;       // upT
  u16* r2 = r1 + W;       // inter [T][I] bf16
  u16* xb = (u16*)d_out;  // bf16 X staged in d_out; dead after gemm12; gemm3 overwrites

  convx_k<<<dim3((T_ * H_) / (256 * 8)), 256, 0, stream>>>(X, xb);
  tconvGU_k<<<dim3(I_ / 64, H_ / 64, E_ * 2), 256, 0, stream>>>(G, U, r0, r1);
  gemm12_k<<<dim3(I_ / 64, T_ / 128), 256, 0, stream>>>(xb, r0, r1, tpe, r2);
  tconvD_k<<<dim3(H_ / 64, I_ / 64, E_), 256, 0, stream>>>(D, r0);
  gemm3_k<<<dim3(H_ / 128, T_ / 128), 256, 0, stream>>>(r2, r0, tpe, out);
}

// Round 2
// 456.847 us; speedup vs baseline: 1.0588x; 1.0156x over previous
//
#include <hip/hip_runtime.h>
#include <hip/hip_bf16.h>

// GroupedMLP: E=8, H=1024, I=2816, T=8192. fp32 in HBM, bf16 MFMA compute.
//   1) prep_k:  fused convx (X fp32->bf16) + tconvGU (gate/up fp32 [E,H,I] -> bf16 [E,I,H])
//               dense-sector loads: every load instr covers full 256B row segments.
//               LDS transpose tile 64x64, stride-68 padding (b64 writes/reads at 4-cy min).
//   2) gemm12:  inter = silu(xb@gate)*(xb@up)  [BK=64, chunk-swizzled; 854 TF ANCHOR - unchanged]
//   3) tconvD:  down fp32 [E,I,H] -> downT bf16 [E,H,I] (dense tile)
//   4) gemm3:   out = inter @ down, BM=128 BN=128 BK=64, NEW: 2-phase double-buffer
//               (STAGE(next) before compute, one barrier/K-step; LDS 64KB free at 2 blk/CU)
// ws: 3 x 46,137,344 B (gateT/downT, upT, inter).

#define E_ 8
#define H_ 1024
#define I_ 2816
#define T_ 8192

typedef unsigned short u16;
typedef __attribute__((ext_vector_type(4))) unsigned short u16x4;
typedef __attribute__((ext_vector_type(8))) short s16x8;
typedef __attribute__((ext_vector_type(8))) unsigned short u16x8;
typedef __attribute__((ext_vector_type(4))) float f32x4;

__device__ __forceinline__ void async16(const u16* g, u16* l) {
  __builtin_amdgcn_global_load_lds((__attribute__((address_space(1))) void*)g,
                                   (__attribute__((address_space(3))) void*)l, 16, 0, 0);
}

__device__ __forceinline__ u16 f2b(float f) {
  union { __hip_bfloat16 h; u16 u; } c;
  c.h = __float2bfloat16(f);
  return c.u;
}

// ---- dense transpose+convert: out[c][r] bf16 = in[r][c] fp32, 64x64 tile ----
// Phase 1: thread t loads a 4x4 subtile: rows rB=(t>>4)*4..+3, cols cQ=(t&15)*4..+3
//          as 4x float4. Per wave-instr: 16 lanes x 16B contiguous = 256B full rows
//          (4 rows/instr) -> 100% sector density. Packs each column's 4 bf16 into one
//          b64 LDS write at lt[(cQ+q)*68 + rB] (stride-68: bank = 2*((c+? )..) spreads
//          to 16 distinct 2-bank slots -> 4-cycle minimum).
// Phase 2: thread t owns out-row c=t>>2, r-segment rs=(t&3)*16: 4x b64 reads
//          (4 lanes/2-bank slot -> 4-cy min), two 16B stores, 32B contiguous per lane,
//          128B contiguous per 4 lanes.
template <int R, int C>
__device__ __forceinline__ void tconv_tile(const float* __restrict__ in,
                                           u16* __restrict__ out,
                                           int bx, int by, int t) {
  __shared__ u16 lt[64 * 68];
  const int c0 = bx * 64, r0 = by * 64;

  const int cQ = (t & 15) * 4;
  const int rB = (t >> 4) * 4;
  const float* p = in + (size_t)(r0 + rB) * C + (c0 + cQ);
  float4 v[4];
#pragma unroll
  for (int j = 0; j < 4; ++j) v[j] = *(const float4*)(p + (size_t)j * C);
  const float* vf = (const float*)v;  // vf[j*4+q] = elem (rB+j, cQ+q)
#pragma unroll
  for (int q = 0; q < 4; ++q) {
    u16x4 w;
    w[0] = f2b(vf[0 * 4 + q]);
    w[1] = f2b(vf[1 * 4 + q]);
    w[2] = f2b(vf[2 * 4 + q]);
    w[3] = f2b(vf[3 * 4 + q]);
    *(u16x4*)(lt + (cQ + q) * 68 + rB) = w;
  }
  __syncthreads();

  const int c = t >> 2;
  const int rs = (t & 3) * 16;
  const u16* rp = lt + c * 68 + rs;
  u16x4 b0 = *(const u16x4*)(rp);
  u16x4 b1 = *(const u16x4*)(rp + 4);
  u16x4 b2 = *(const u16x4*)(rp + 8);
  u16x4 b3 = *(const u16x4*)(rp + 12);
  u16x8 o0 = __builtin_shufflevector(b0, b1, 0, 1, 2, 3, 4, 5, 6, 7);
  u16x8 o1 = __builtin_shufflevector(b2, b3, 0, 1, 2, 3, 4, 5, 6, 7);
  u16* op = out + (size_t)(c0 + c) * R + (r0 + rs);
  *(u16x8*)(op) = o0;
  *(u16x8*)(op + 8) = o1;
}

// ---------------- fused prep: convx (4096 blocks) + tconvGU (11264 blocks) ----------------
__global__ __launch_bounds__(256) void prep_k(const float* __restrict__ X,
                                              const float* __restrict__ G,
                                              const float* __restrict__ U,
                                              u16* __restrict__ xb,
                                              u16* __restrict__ GT,
                                              u16* __restrict__ UT) {
  const int bid = blockIdx.x;
  const int t = threadIdx.x;
  if (bid < 4096) {
    // convx: X fp32 -> bf16, 8 elems/thread
    size_t i = ((size_t)bid * 256 + t) * 8;
    float4 v0 = *(const float4*)(X + i);
    float4 v1 = *(const float4*)(X + i + 4);
    u16x8 b;
    b[0] = f2b(v0.x); b[1] = f2b(v0.y); b[2] = f2b(v0.z); b[3] = f2b(v0.w);
    b[4] = f2b(v1.x); b[5] = f2b(v1.y); b[6] = f2b(v1.z); b[7] = f2b(v1.w);
    *(u16x8*)(xb + i) = b;
  } else {
    int b = bid - 4096;
    const int bx = b % 44; b /= 44;   // I tile
    const int by = b % 16; b /= 16;   // H tile
    const int z = b;                  // expert*2 + (gate/up)
    const size_t eoff = (size_t)(z >> 1) * (size_t)H_ * I_;
    const float* in = ((z & 1) ? U : G) + eoff;
    u16* out = ((z & 1) ? UT : GT) + eoff;
    tconv_tile<H_, I_>(in, out, bx, by, t);
  }
}

__global__ __launch_bounds__(256) void tconvD_k(const float* __restrict__ D,
                                                u16* __restrict__ DT) {
  const size_t eoff = (size_t)blockIdx.z * (size_t)H_ * I_;
  tconv_tile<I_, H_>(D + eoff, DT + eoff, blockIdx.x, blockIdx.y, threadIdx.x);
}

// ---------------- fused gate/up GEMM + SwiGLU, BK=64, chunk-swizzled (ANCHOR, unchanged) ----------------
__global__ __launch_bounds__(256, 2) void gemm12_k(
    const u16* __restrict__ X, const u16* __restrict__ GT,
    const u16* __restrict__ UT, const int* __restrict__ tpe,
    u16* __restrict__ inter) {
  __shared__ u16 sA[128 * 64];
  __shared__ u16 sG[64 * 64];
  __shared__ u16 sU[64 * 64];
  const int t = threadIdx.x;
  const int m0 = blockIdx.y * 128;
  const int n0 = blockIdx.x * 64;

  int e = 0, seg_end = T_;
  {
    int s = 0;
    for (int i = 0; i < E_; ++i) {
      int c = tpe[i];
      if (m0 < s + c) { e = i; seg_end = s + c; break; }
      s += c;
    }
  }
  const u16* GTe = GT + (size_t)e * I_ * H_;
  const u16* UTe = UT + (size_t)e * I_ * H_;

  const int sj = ((t & 7) ^ ((t >> 3) & 7)) * 8;
  const u16* gA = X + (size_t)(m0 + (t >> 3)) * H_ + sj;
  const u16* gG = GTe + (size_t)(n0 + (t >> 3)) * H_ + sj;
  const u16* gU = UTe + (size_t)(n0 + (t >> 3)) * H_ + sj;
  u16* lA = sA + t * 8;
  u16* lG = sG + t * 8;
  u16* lU = sU + t * 8;

  const int l = t & 63, w = t >> 6;
  const int wm = (w & 1) * 64, wn = (w >> 1) * 32;
  const int c0 = (((l >> 4) ^ (l & 7))) * 8;
  const u16* fA = sA + (size_t)(wm + (l & 15)) * 64;
  const u16* fG = sG + (size_t)(wn + (l & 15)) * 64;
  const u16* fU = sU + (size_t)(wn + (l & 15)) * 64;

  f32x4 accG[4][2], accU[4][2];
#pragma unroll
  for (int mi = 0; mi < 4; ++mi)
#pragma unroll
    for (int ni = 0; ni < 2; ++ni) {
      accG[mi][ni] = (f32x4){0.f, 0.f, 0.f, 0.f};
      accU[mi][ni] = (f32x4){0.f, 0.f, 0.f, 0.f};
    }

  for (int k0 = 0; k0 < H_; k0 += 64) {
    async16(gA + k0, lA);
    async16(gA + 32 * H_ + k0, lA + 2048);
    async16(gA + 64 * H_ + k0, lA + 4096);
    async16(gA + 96 * H_ + k0, lA + 6144);
    async16(gG + k0, lG);
    async16(gG + 32 * H_ + k0, lG + 2048);
    async16(gU + k0, lU);
    async16(gU + 32 * H_ + k0, lU + 2048);
    __syncthreads();
#pragma unroll
    for (int ks = 0; ks < 2; ++ks) {
      const int co = c0 ^ (ks * 32);
      s16x8 aF[4], gF[2], uF[2];
#pragma unroll
      for (int mi = 0; mi < 4; ++mi) aF[mi] = *(const s16x8*)(fA + mi * 1024 + co);
#pragma unroll
      for (int ni = 0; ni < 2; ++ni) {
        gF[ni] = *(const s16x8*)(fG + ni * 1024 + co);
        uF[ni] = *(const s16x8*)(fU + ni * 1024 + co);
      }
#pragma unroll
      for (int mi = 0; mi < 4; ++mi)
#pragma unroll
        for (int ni = 0; ni < 2; ++ni) {
          accG[mi][ni] = __builtin_amdgcn_mfma_f32_16x16x32_bf16(aF[mi], gF[ni], accG[mi][ni], 0, 0, 0);
          accU[mi][ni] = __builtin_amdgcn_mfma_f32_16x16x32_bf16(aF[mi], uF[ni], accU[mi][ni], 0, 0, 0);
        }
    }
    __syncthreads();
  }

  const int colb = l & 15, rowb = (l >> 4) * 4;
#pragma unroll
  for (int mi = 0; mi < 4; ++mi)
#pragma unroll
    for (int ni = 0; ni < 2; ++ni) {
      const size_t gcol = (size_t)(n0 + wn + ni * 16 + colb);
#pragma unroll
      for (int r = 0; r < 4; ++r) {
        int grow = m0 + wm + mi * 16 + rowb + r;
        if (grow < seg_end) {
          float o1 = accG[mi][ni][r];
          float o2 = accU[mi][ni][r];
          float sv = o1 / (1.f + __expf(-o1));
          inter[(size_t)grow * I_ + gcol] = f2b(sv * o2);
        }
      }
    }
}

// ------- down-proj GEMM: BM=128, BN=128, BK=64, 2-phase double-buffered -------
// grid 8 x 64 = 512 blocks = 2/CU (grid-capped, so 64KB LDS costs no occupancy).
// Per K-step: STAGE(next buf) issued BEFORE compute(cur); compiler's vmcnt(0) drain
// lands at the single end-of-step barrier -> load latency hides under 32 MFMA.
__global__ __launch_bounds__(256, 2) void gemm3_k(
    const u16* __restrict__ A, const u16* __restrict__ DT,
    const int* __restrict__ tpe, float* __restrict__ out) {
  __shared__ u16 sA[2][128 * 64];  // 32 KB
  __shared__ u16 sB[2][128 * 64];  // 32 KB
  const int t = threadIdx.x;
  const int m0 = blockIdx.y * 128;
  const int n0 = blockIdx.x * 128;

  int e = 0, seg_end = T_;
  {
    int s = 0;
    for (int i = 0; i < E_; ++i) {
      int c = tpe[i];
      if (m0 < s + c) { e = i; seg_end = s + c; break; }
      s += c;
    }
  }
  const u16* DTe = DT + (size_t)e * H_ * I_;

  const int sj = ((t & 7) ^ ((t >> 3) & 7)) * 8;
  const u16* gA = A + (size_t)(m0 + (t >> 3)) * I_ + sj;
  const u16* gB = DTe + (size_t)(n0 + (t >> 3)) * I_ + sj;
  const int toff = t * 8;

  const int l = t & 63, w = t >> 6;
  const int wm = (w & 1) * 64, wn = (w >> 1) * 64;
  const int c0 = (((l >> 4) ^ (l & 7))) * 8;
  const int foff = (wm + (l & 15)) * 64;
  const int goff = (wn + (l & 15)) * 64;

  f32x4 acc[4][4];
#pragma unroll
  for (int mi = 0; mi < 4; ++mi)
#pragma unroll
    for (int ni = 0; ni < 4; ++ni) acc[mi][ni] = (f32x4){0.f, 0.f, 0.f, 0.f};

#define STAGE3(buf, k0)                                   \
  {                                                       \
    u16* dA = &sA[buf][0] + toff;                         \
    u16* dB = &sB[buf][0] + toff;                         \
    async16(gA + (k0), dA);                               \
    async16(gA + 32 * I_ + (k0), dA + 2048);              \
    async16(gA + 64 * I_ + (k0), dA + 4096);              \
    async16(gA + 96 * I_ + (k0), dA + 6144);              \
    async16(gB + (k0), dB);                               \
    async16(gB + 32 * I_ + (k0), dB + 2048);              \
    async16(gB + 64 * I_ + (k0), dB + 4096);              \
    async16(gB + 96 * I_ + (k0), dB + 6144);              \
  }

  STAGE3(0, 0);
  __syncthreads();
  int cur = 0;
  for (int k0 = 0; k0 < I_; k0 += 64) {
    if (k0 + 64 < I_) STAGE3(cur ^ 1, k0 + 64);
    const u16* fA = &sA[cur][0] + foff;
    const u16* fB = &sB[cur][0] + goff;
#pragma unroll
    for (int ks = 0; ks < 2; ++ks) {
      const int co = c0 ^ (ks * 32);
      s16x8 aF[4], bF[4];
#pragma unroll
      for (int mi = 0; mi < 4; ++mi) aF[mi] = *(const s16x8*)(fA + mi * 1024 + co);
#pragma unroll
      for (int ni = 0; ni < 4; ++ni) bF[ni] = *(const s16x8*)(fB + ni * 1024 + co);
#pragma unroll
      for (int mi = 0; mi < 4; ++mi)
#pragma unroll
        for (int ni = 0; ni < 4; ++ni)
          acc[mi][ni] = __builtin_amdgcn_mfma_f32_16x16x32_bf16(aF[mi], bF[ni], acc[mi][ni], 0, 0, 0);
    }
    __syncthreads();
    cur ^= 1;
  }
#undef STAGE3

  const int colb = l & 15, rowb = (l >> 4) * 4;
#pragma unroll
  for (int mi = 0; mi < 4; ++mi)
#pragma unroll
    for (int ni = 0; ni < 4; ++ni) {
      const size_t gcol = (size_t)(n0 + wn + ni * 16 + colb);
#pragma unroll
      for (int r = 0; r < 4; ++r) {
        int grow = m0 + wm + mi * 16 + rowb + r;
        if (grow < seg_end) out[(size_t)grow * H_ + gcol] = acc[mi][ni][r];
      }
    }
}

extern "C" void kernel_launch(void* const* d_in, const int* in_sizes, int n_in,
                              void* d_out, int out_size, void* d_ws, size_t ws_size,
                              hipStream_t stream) {
  const float* X = (const float*)d_in[0];
  const float* G = (const float*)d_in[1];
  const float* U = (const float*)d_in[2];
  const float* D = (const float*)d_in[3];
  const int* tpe = (const int*)d_in[4];
  float* out = (float*)d_out;

  const size_t W = (size_t)E_ * H_ * I_;
  if (ws_size < 3 * W * sizeof(u16)) return;
  u16* r0 = (u16*)d_ws;   // gateT, later downT
  u16* r1 = r0 + W;       // upT
  u16* r2 = r1 + W;       // inter [T][I] bf16
  u16* xb = (u16*)d_out;  // bf16 X staged in d_out; dead after gemm12; gemm3 overwrites

  prep_k<<<dim3(4096 + 11264), 256, 0, stream>>>(X, G, U, xb, r0, r1);
  gemm12_k<<<dim3(I_ / 64, T_ / 128), 256, 0, stream>>>(xb, r0, r1, tpe, r2);
  tconvD_k<<<dim3(H_ / 64, I_ / 64, E_), 256, 0, stream>>>(D, r0);
  gemm3_k<<<dim3(H_ / 128, T_ / 128), 256, 0, stream>>>(r2, r0, tpe, out);
}